// Round 1
// baseline (237.042 us; speedup 1.0000x reference)
//
#include <hip/hip_runtime.h>

typedef float f32x4 __attribute__((ext_vector_type(4)));
typedef short s16x8 __attribute__((ext_vector_type(8)));
typedef unsigned short u16;
typedef unsigned short u16x4 __attribute__((ext_vector_type(4)));

#define DI __device__ __forceinline__

constexpr int B_ = 2, S_ = 2048, E_ = 1024, H_ = 16, DH = 64, M_ = B_ * S_;
// 1/sqrt(64) * log2(e): scores land in log2 domain -> exp2f for softmax
constexpr float QSCALE = 0.125f * 1.4426950408889634f;

DI u16 f2bf(float f) {
    unsigned u = __float_as_uint(f);
    u += 0x7fffu + ((u >> 16) & 1u);
    return (u16)(u >> 16);
}

DI void mfma(f32x4& d, s16x8 a, s16x8 b) {
    asm("v_mfma_f32_16x16x32_bf16 %0, %1, %2, %0" : "+v"(d) : "v"(a), "v"(b));
}

// ---- preprocess kernels -------------------------------------------------

__global__ __launch_bounds__(256) void cvt_bf16(const float* __restrict__ in,
                                                u16* __restrict__ out, int n4) {
    int i = blockIdx.x * 256 + threadIdx.x;
    if (i < n4) {
        float4 v = ((const float4*)in)[i];
        u16x4 o;
        o.x = f2bf(v.x); o.y = f2bf(v.y); o.z = f2bf(v.z); o.w = f2bf(v.w);
        ((u16x4*)out)[i] = o;
    }
}

// W [K=E][N=E] f32 -> Wt [N][K] bf16
__global__ __launch_bounds__(256) void wtrans(const float* __restrict__ in,
                                              u16* __restrict__ out) {
    __shared__ float t[64][65];
    int k0 = blockIdx.x * 64, n0 = blockIdx.y * 64;
    int tx = threadIdx.x & 63, ty = threadIdx.x >> 6;
#pragma unroll
    for (int i = 0; i < 16; i++) {
        int r = i * 4 + ty;
        t[r][tx] = in[(k0 + r) * E_ + n0 + tx];
    }
    __syncthreads();
#pragma unroll
    for (int i = 0; i < 16; i++) {
        int r = i * 4 + ty;
        out[(n0 + r) * E_ + k0 + tx] = f2bf(t[tx][r]);
    }
}

// mask [B][S][S] int -> bit-packed transposed words mt[b][q>>5][kk], bit=q&31
__global__ __launch_bounds__(256) void mpack(const int* __restrict__ mask,
                                             unsigned* __restrict__ mt) {
    __shared__ int tle[64][65];
    int q0 = blockIdx.x * 64, k0 = blockIdx.y * 64, b = blockIdx.z;
    const int* mb = mask + b * S_ * S_;
    int tx = threadIdx.x & 63, ty = threadIdx.x >> 6;
#pragma unroll
    for (int i = 0; i < 16; i++) {
        int r = i * 4 + ty;
        tle[r][tx] = mb[(q0 + r) * S_ + k0 + tx];
    }
    __syncthreads();
    if (threadIdx.x < 128) {
        int kk = threadIdx.x & 63, qw = threadIdx.x >> 6;
        unsigned w = 0;
#pragma unroll
        for (int j = 0; j < 32; j++) w |= (tle[qw * 32 + j][kk] ? 1u : 0u) << j;
        mt[(b * (S_ / 32) + (q0 >> 5) + qw) * S_ + k0 + kk] = w;
    }
}

// ---- 128x128 bf16 MFMA GEMM, B^T input ---------------------------------
// MODE 0: Q (scale QSCALE, layout [B,H,S,64])  1: K (same layout)
// MODE 2: V transposed ([B,H,64,S])            3: O-proj (f32 out [M,E])
template <int MODE>
__global__ __launch_bounds__(256) void proj(const u16* __restrict__ A,
                                            const u16* __restrict__ Bt,
                                            const float* __restrict__ bias,
                                            u16* __restrict__ ob,
                                            float* __restrict__ of) {
    __shared__ u16 sA[128 * 32], sB[128 * 32];
    const int tid = threadIdx.x, lane = tid & 63, wid = tid >> 6;
    const int g = lane >> 4, lr = lane & 15;
    const int wr = wid >> 1, wc = wid & 1;
    const int row0 = (blockIdx.x >> 3) * 128, col0 = (blockIdx.x & 7) * 128;

    f32x4 acc[4][4] = {};
    for (int kt = 0; kt < E_ / 32; kt++) {
        int k0 = kt * 32;
        s16x8 av[2], bv2[2];
#pragma unroll
        for (int p = 0; p < 2; p++) {
            int L = p * 256 + tid, r = L >> 2, cb = L & 3;
            av[p]  = *(const s16x8*)(A  + (row0 + r) * E_ + k0 + cb * 8);
            bv2[p] = *(const s16x8*)(Bt + (col0 + r) * E_ + k0 + cb * 8);
        }
        __syncthreads();
#pragma unroll
        for (int p = 0; p < 2; p++) {
            int L = p * 256 + tid, r = L >> 2, cb = L & 3, pb = cb ^ ((r >> 1) & 3);
            *(s16x8*)(sA + r * 32 + pb * 8) = av[p];
            *(s16x8*)(sB + r * 32 + pb * 8) = bv2[p];
        }
        __syncthreads();
        s16x8 af[4], bfr[4];
#pragma unroll
        for (int m = 0; m < 4; m++) {
            int r = wr * 64 + m * 16 + lr;
            af[m] = *(const s16x8*)(sA + r * 32 + (g ^ ((r >> 1) & 3)) * 8);
        }
#pragma unroll
        for (int n = 0; n < 4; n++) {
            int r = wc * 64 + n * 16 + lr;
            bfr[n] = *(const s16x8*)(sB + r * 32 + (g ^ ((r >> 1) & 3)) * 8);
        }
#pragma unroll
        for (int m = 0; m < 4; m++)
#pragma unroll
            for (int n = 0; n < 4; n++) mfma(acc[m][n], af[m], bfr[n]);
    }

#pragma unroll
    for (int n = 0; n < 4; n++) {
        int c = col0 + wc * 64 + n * 16 + lr;
        float bb = bias[c];
#pragma unroll
        for (int m = 0; m < 4; m++) {
            int rb = row0 + wr * 64 + m * 16 + g * 4;
            if constexpr (MODE == 3) {
#pragma unroll
                for (int i = 0; i < 4; i++) of[(rb + i) * E_ + c] = acc[m][n][i] + bb;
            } else if constexpr (MODE == 2) {
                int b = rb >> 11, s = rb & (S_ - 1);
                int h = c >> 6, dh = c & 63;
                u16x4 pk;
                pk.x = f2bf(acc[m][n][0] + bb);
                pk.y = f2bf(acc[m][n][1] + bb);
                pk.z = f2bf(acc[m][n][2] + bb);
                pk.w = f2bf(acc[m][n][3] + bb);
                *(u16x4*)(ob + ((b * H_ + h) * DH + dh) * S_ + s) = pk;
            } else {
                const float sc = (MODE == 0) ? QSCALE : 1.0f;
#pragma unroll
                for (int i = 0; i < 4; i++) {
                    int r = rb + i, b = r >> 11, s = r & (S_ - 1);
                    int h = c >> 6, dh = c & 63;
                    ob[((b * H_ + h) * S_ + s) * DH + dh] = f2bf((acc[m][n][i] + bb) * sc);
                }
            }
        }
    }
}

// ---- flash attention ----------------------------------------------------
// grid (S/128, H, B), 256 threads = 4 waves x 32 q-rows.
__global__ __launch_bounds__(256) void attn(const u16* __restrict__ Q,
                                            const u16* __restrict__ K,
                                            const u16* __restrict__ V,
                                            const unsigned* __restrict__ mt,
                                            u16* __restrict__ ctx) {
    __shared__ u16 sK[128 * 64];   // [kk][d], swizzled
    __shared__ u16 sV[64 * 128];   // [d][kk], swizzled
    __shared__ u16 sP[128 * 128];  // [q][kk], swizzled
    const int tid = threadIdx.x, lane = tid & 63, wid = tid >> 6;
    const int g = lane >> 4, lr = lane & 15;
    const int q0 = blockIdx.x * 128, h = blockIdx.y, b = blockIdx.z;
    const u16* qb = Q + ((b * H_ + h) * S_ + q0) * DH;
    const u16* kb = K + (b * H_ + h) * S_ * DH;
    const u16* vb = V + (b * H_ + h) * DH * S_;
    const unsigned* mb = mt + (b * (S_ / 32) + ((q0 + wid * 32) >> 5)) * S_;

    // Q fragments in registers (pre-scaled at projection time)
    s16x8 qf[2][2];
#pragma unroll
    for (int m = 0; m < 2; m++)
#pragma unroll
        for (int dc = 0; dc < 2; dc++)
            qf[m][dc] = *(const s16x8*)(qb + (wid * 32 + m * 16 + lr) * DH + dc * 32 + g * 8);

    f32x4 o[2][4] = {};
    float mrun[2][4], lrun[2][4];
#pragma unroll
    for (int m = 0; m < 2; m++)
#pragma unroll
        for (int i = 0; i < 4; i++) { mrun[m][i] = -3e38f; lrun[m][i] = 0.f; }

    for (int kt = 0; kt < S_ / 128; kt++) {
        int k0 = kt * 128;
        s16x8 kv[4], vv[4];
#pragma unroll
        for (int p = 0; p < 4; p++) {
            int L = p * 256 + tid;
            kv[p] = *(const s16x8*)(kb + (k0 + (L >> 3)) * DH + (L & 7) * 8);
            vv[p] = *(const s16x8*)(vb + (L >> 4) * S_ + k0 + (L & 15) * 8);
        }
        __syncthreads();  // previous tile fully consumed
#pragma unroll
        for (int p = 0; p < 4; p++) {
            int L = p * 256 + tid;
            int rk = L >> 3, ck = L & 7;
            *(s16x8*)(sK + rk * 64 + (ck ^ (rk & 7)) * 8) = kv[p];
            int rv = L >> 4, cv = L & 15;
            *(s16x8*)(sV + rv * 128 + (cv ^ (rv & 7)) * 8) = vv[p];
        }
        __syncthreads();

        // scores = Q K^T (log2 domain)
        f32x4 sc[2][8];
        const f32x4 zero = {0.f, 0.f, 0.f, 0.f};
#pragma unroll
        for (int n = 0; n < 8; n++) {
            int r = n * 16 + lr;
            s16x8 kf0 = *(const s16x8*)(sK + r * 64 + ((0 * 4 + g) ^ (r & 7)) * 8);
            s16x8 kf1 = *(const s16x8*)(sK + r * 64 + ((4 + g) ^ (r & 7)) * 8);
#pragma unroll
            for (int m = 0; m < 2; m++) {
                sc[m][n] = zero;
                mfma(sc[m][n], qf[m][0], kf0);
                mfma(sc[m][n], qf[m][1], kf1);
            }
        }
        // mask
#pragma unroll
        for (int n = 0; n < 8; n++) {
            unsigned wbits = mb[k0 + n * 16 + lr];
#pragma unroll
            for (int m = 0; m < 2; m++)
#pragma unroll
                for (int i = 0; i < 4; i++)
                    if (!((wbits >> (m * 16 + g * 4 + i)) & 1u)) sc[m][n][i] = -1e9f;
        }
        // online softmax (exp2 domain)
#pragma unroll
        for (int m = 0; m < 2; m++) {
            float tmax[4], fac[4], rs[4];
#pragma unroll
            for (int i = 0; i < 4; i++) {
                float v = sc[m][0][i];
#pragma unroll
                for (int n = 1; n < 8; n++) v = fmaxf(v, sc[m][n][i]);
#pragma unroll
                for (int d = 1; d < 16; d <<= 1) v = fmaxf(v, __shfl_xor(v, d));
                tmax[i] = v;
            }
#pragma unroll
            for (int i = 0; i < 4; i++) {
                float mn = fmaxf(mrun[m][i], tmax[i]);
                fac[i] = exp2f(mrun[m][i] - mn);
                mrun[m][i] = mn;
                rs[i] = 0.f;
            }
#pragma unroll
            for (int nn = 0; nn < 4; nn++)
#pragma unroll
                for (int i = 0; i < 4; i++) o[m][nn][i] *= fac[i];
#pragma unroll
            for (int n = 0; n < 8; n++) {
                int colbase = n * 16 + lr;
#pragma unroll
                for (int i = 0; i < 4; i++) {
                    float p = exp2f(sc[m][n][i] - mrun[m][i]);
                    rs[i] += p;
                    int row = wid * 32 + m * 16 + g * 4 + i;
                    sP[row * 128 + (colbase ^ ((row & 7) * 8))] = f2bf(p);
                }
            }
#pragma unroll
            for (int i = 0; i < 4; i++) {
                float v = rs[i];
#pragma unroll
                for (int d = 1; d < 16; d <<= 1) v += __shfl_xor(v, d);
                lrun[m][i] = lrun[m][i] * fac[i] + v;
            }
        }
        // PV: o += P V   (wave reads only its own 32 P-rows; intra-wave lgkm order suffices)
#pragma unroll
        for (int kc = 0; kc < 4; kc++) {
            s16x8 pa[2];
#pragma unroll
            for (int m = 0; m < 2; m++) {
                int row = wid * 32 + m * 16 + lr;
                pa[m] = *(const s16x8*)(sP + row * 128 + ((kc * 32 + g * 8) ^ ((row & 7) * 8)));
            }
#pragma unroll
            for (int n = 0; n < 4; n++) {
                int rv = n * 16 + lr;
                s16x8 vf = *(const s16x8*)(sV + rv * 128 + ((kc * 4 + g) ^ (rv & 7)) * 8);
                mfma(o[0][n], pa[0], vf);
                mfma(o[1][n], pa[1], vf);
            }
        }
    }
    // normalize + store ctx [B,S,E] bf16
#pragma unroll
    for (int m = 0; m < 2; m++)
#pragma unroll
        for (int n = 0; n < 4; n++)
#pragma unroll
            for (int i = 0; i < 4; i++) {
                int sq = q0 + wid * 32 + m * 16 + g * 4 + i;
                float v = o[m][n][i] / lrun[m][i];
                ctx[(b * S_ + sq) * E_ + h * DH + n * 16 + lr] = f2bf(v);
            }
}

// ---- launch -------------------------------------------------------------

extern "C" void kernel_launch(void* const* d_in, const int* in_sizes, int n_in,
                              void* d_out, int out_size, void* d_ws, size_t ws_size,
                              hipStream_t stream) {
    const float* x  = (const float*)d_in[0];
    const int* mask = (const int*)d_in[1];
    const float* Wq = (const float*)d_in[2]; const float* bq = (const float*)d_in[3];
    const float* Wk = (const float*)d_in[4]; const float* bk = (const float*)d_in[5];
    const float* Wv = (const float*)d_in[6]; const float* bv = (const float*)d_in[7];
    const float* Wo = (const float*)d_in[8]; const float* bo = (const float*)d_in[9];
    float* out = (float*)d_out;

    char* ws = (char*)d_ws;
    u16* xb  = (u16*)(ws);                       // 8 MB  [M,E] bf16
    u16* Wqt = (u16*)(ws + (8u  << 20));         // 2 MB  [E,E] B^T
    u16* Wkt = (u16*)(ws + (10u << 20));
    u16* Wvt = (u16*)(ws + (12u << 20));
    u16* Wot = (u16*)(ws + (14u << 20));
    u16* Qh  = (u16*)(ws + (16u << 20));         // 8 MB  [B,H,S,64] (pre-scaled)
    u16* Kh  = (u16*)(ws + (24u << 20));         // 8 MB  [B,H,S,64]
    u16* Vt  = (u16*)(ws + (32u << 20));         // 8 MB  [B,H,64,S]
    u16* ctx = (u16*)(ws + (40u << 20));         // 8 MB  [M,E]
    unsigned* mt = (unsigned*)(ws + (48u << 20)); // 1 MB  packed mask

    cvt_bf16<<<(M_ * E_ / 4 + 255) / 256, 256, 0, stream>>>(x, xb, M_ * E_ / 4);
    dim3 tg(E_ / 64, E_ / 64);
    wtrans<<<tg, 256, 0, stream>>>(Wq, Wqt);
    wtrans<<<tg, 256, 0, stream>>>(Wk, Wkt);
    wtrans<<<tg, 256, 0, stream>>>(Wv, Wvt);
    wtrans<<<tg, 256, 0, stream>>>(Wo, Wot);
    mpack<<<dim3(S_ / 64, S_ / 64, B_), 256, 0, stream>>>(mask, mt);

    proj<0><<<(M_ / 128) * (E_ / 128), 256, 0, stream>>>(xb, Wqt, bq, Qh, nullptr);
    proj<1><<<(M_ / 128) * (E_ / 128), 256, 0, stream>>>(xb, Wkt, bk, Kh, nullptr);
    proj<2><<<(M_ / 128) * (E_ / 128), 256, 0, stream>>>(xb, Wvt, bv, Vt, nullptr);

    attn<<<dim3(S_ / 128, H_, B_), 256, 0, stream>>>(Qh, Kh, Vt, mt, ctx);

    proj<3><<<(M_ / 128) * (E_ / 128), 256, 0, stream>>>(ctx, Wot, bo, nullptr, out);
}

// Round 2
// 190.148 us; speedup vs baseline: 1.2466x; 1.2466x over previous
//
#include <hip/hip_runtime.h>

typedef float f32x4 __attribute__((ext_vector_type(4)));
typedef short s16x8 __attribute__((ext_vector_type(8)));
typedef unsigned short u16;
typedef unsigned short u16x4 __attribute__((ext_vector_type(4)));
typedef unsigned int u32x2 __attribute__((ext_vector_type(2)));

#define DI __device__ __forceinline__

constexpr int B_ = 2, S_ = 2048, E_ = 1024, H_ = 16, DH = 64, M_ = B_ * S_;
// 1/sqrt(64) * log2(e): scores land in log2 domain -> exp2f for softmax
constexpr float QSCALE = 0.125f * 1.4426950408889634f;

DI u16 f2bf(float f) {
    unsigned u = __float_as_uint(f);
    u += 0x7fffu + ((u >> 16) & 1u);
    return (u16)(u >> 16);
}

DI unsigned cvtpk(float lo, float hi) {
    unsigned r;
    asm("v_cvt_pk_bf16_f32 %0, %1, %2" : "=v"(r) : "v"(lo), "v"(hi));
    return r;
}

DI void mfma(f32x4& d, s16x8 a, s16x8 b) {
    asm("v_mfma_f32_16x16x32_bf16 %0, %1, %2, %0" : "+v"(d) : "v"(a), "v"(b));
}

// ---- preprocess kernels -------------------------------------------------

__global__ __launch_bounds__(256) void cvt_bf16(const float* __restrict__ in,
                                                u16* __restrict__ out, int n4) {
    int i = blockIdx.x * 256 + threadIdx.x;
    if (i < n4) {
        float4 v = ((const float4*)in)[i];
        u16x4 o;
        o.x = f2bf(v.x); o.y = f2bf(v.y); o.z = f2bf(v.z); o.w = f2bf(v.w);
        ((u16x4*)out)[i] = o;
    }
}

// W [K=E][N=E] f32 -> Wt [N][K] bf16 (write into a row-offset region for fused QKV)
__global__ __launch_bounds__(256) void wtrans(const float* __restrict__ in,
                                              u16* __restrict__ out) {
    __shared__ float t[64][65];
    int k0 = blockIdx.x * 64, n0 = blockIdx.y * 64;
    int tx = threadIdx.x & 63, ty = threadIdx.x >> 6;
#pragma unroll
    for (int i = 0; i < 16; i++) {
        int r = i * 4 + ty;
        t[r][tx] = in[(k0 + r) * E_ + n0 + tx];
    }
    __syncthreads();
#pragma unroll
    for (int i = 0; i < 16; i++) {
        int r = i * 4 + ty;
        out[(n0 + r) * E_ + k0 + tx] = f2bf(t[tx][r]);
    }
}

// mask [B][S][S] int -> k-packed words mk[b][k>>5][q], bit = k&31
__global__ __launch_bounds__(256) void mpackK(const int* __restrict__ mask,
                                              unsigned* __restrict__ mk) {
    int t = blockIdx.x * 256 + threadIdx.x;  // (b, kw, q), q fastest
    int q = t & (S_ - 1);
    int kw = (t >> 11) & 63;
    int b = t >> 17;
    const int* mp = mask + ((size_t)(b * S_ + q)) * S_ + kw * 32;
    unsigned w = 0;
#pragma unroll
    for (int j = 0; j < 32; j++) w |= (mp[j] != 0 ? 1u : 0u) << j;
    mk[t] = w;
}

// ---- 128x128 bf16 MFMA GEMM, B^T input ---------------------------------
// MODE 0: fused QKV (Bt rows 0..3071; epilogue routes by region)
// MODE 3: O-proj (f32 out [M,E])
template <int MODE>
__global__ __launch_bounds__(256) void proj(const u16* __restrict__ A,
                                            const u16* __restrict__ Bt,
                                            const float* __restrict__ b0,
                                            const float* __restrict__ b1,
                                            const float* __restrict__ b2,
                                            u16* __restrict__ Qh, u16* __restrict__ Kh,
                                            u16* __restrict__ Vt,
                                            float* __restrict__ of) {
    __shared__ u16 sA[128 * 32], sB[128 * 32];
    const int tid = threadIdx.x, lane = tid & 63, wid = tid >> 6;
    const int g = lane >> 4, lr = lane & 15;
    const int wr = wid >> 1, wc = wid & 1;
    constexpr int NCT = (MODE == 0) ? 24 : 8;
    const int rt = blockIdx.x / NCT, ct = blockIdx.x % NCT;
    const int row0 = rt * 128, col0 = ct * 128;

    f32x4 acc[4][4] = {};
    for (int kt = 0; kt < E_ / 32; kt++) {
        int k0 = kt * 32;
        s16x8 av[2], bv2[2];
#pragma unroll
        for (int p = 0; p < 2; p++) {
            int L = p * 256 + tid, r = L >> 2, cb = L & 3;
            av[p]  = *(const s16x8*)(A  + (size_t)(row0 + r) * E_ + k0 + cb * 8);
            bv2[p] = *(const s16x8*)(Bt + (size_t)(col0 + r) * E_ + k0 + cb * 8);
        }
        __syncthreads();
#pragma unroll
        for (int p = 0; p < 2; p++) {
            int L = p * 256 + tid, r = L >> 2, cb = L & 3, pb = cb ^ ((r >> 1) & 3);
            *(s16x8*)(sA + r * 32 + pb * 8) = av[p];
            *(s16x8*)(sB + r * 32 + pb * 8) = bv2[p];
        }
        __syncthreads();
        s16x8 af[4], bfr[4];
#pragma unroll
        for (int m = 0; m < 4; m++) {
            int r = wr * 64 + m * 16 + lr;
            af[m] = *(const s16x8*)(sA + r * 32 + (g ^ ((r >> 1) & 3)) * 8);
        }
#pragma unroll
        for (int n = 0; n < 4; n++) {
            int r = wc * 64 + n * 16 + lr;
            bfr[n] = *(const s16x8*)(sB + r * 32 + (g ^ ((r >> 1) & 3)) * 8);
        }
#pragma unroll
        for (int m = 0; m < 4; m++)
#pragma unroll
            for (int n = 0; n < 4; n++) mfma(acc[m][n], af[m], bfr[n]);
    }

    if constexpr (MODE == 3) {
#pragma unroll
        for (int n = 0; n < 4; n++) {
            int c = col0 + wc * 64 + n * 16 + lr;
            float bb = b0[c];
#pragma unroll
            for (int m = 0; m < 4; m++) {
                int rb = row0 + wr * 64 + m * 16 + g * 4;
#pragma unroll
                for (int i = 0; i < 4; i++) of[(size_t)(rb + i) * E_ + c] = acc[m][n][i] + bb;
            }
        }
    } else {
        const int region = col0 >> 10;  // block-uniform: 0=Q 1=K 2=V
        const float* bias = region == 0 ? b0 : (region == 1 ? b1 : b2);
        const float scl = region == 0 ? QSCALE : 1.0f;
        u16* dst = region == 0 ? Qh : Kh;
#pragma unroll
        for (int n = 0; n < 4; n++) {
            int ccol = (col0 & 1023) + wc * 64 + n * 16 + lr;  // 0..1023
            float bb = bias[ccol];
            int h = ccol >> 6, dh = ccol & 63;
#pragma unroll
            for (int m = 0; m < 4; m++) {
                int rb = row0 + wr * 64 + m * 16 + g * 4;
                int b = rb >> 11, s = rb & (S_ - 1);
                if (region == 2) {
                    u16x4 pk;
                    pk.x = f2bf(acc[m][n][0] + bb);
                    pk.y = f2bf(acc[m][n][1] + bb);
                    pk.z = f2bf(acc[m][n][2] + bb);
                    pk.w = f2bf(acc[m][n][3] + bb);
                    *(u16x4*)(Vt + ((size_t)((b * H_ + h) * DH + dh)) * S_ + s) = pk;
                } else {
#pragma unroll
                    for (int i = 0; i < 4; i++) {
                        int r = rb + i, bb2 = r >> 11, s2 = r & (S_ - 1);
                        dst[((size_t)((bb2 * H_ + h) * S_) + s2) * DH + dh] =
                            f2bf((acc[m][n][i] + bb) * scl);
                    }
                }
            }
        }
    }
}

// ---- flash attention, swapped-operand layout ----------------------------
// grid (S/128, H, B), 256 threads = 4 waves x 32 q-rows each.
// QK^T: mfma(A=K, B=Q) -> lane holds scores for q = lr (all k in regs).
// PV:   mfma(A=V^T, B=P) -> o[q=lr][d in regs]; rescale is lane-uniform.
__global__ __launch_bounds__(256, 2) void attn(const u16* __restrict__ Q,
                                               const u16* __restrict__ K,
                                               const u16* __restrict__ V,
                                               const unsigned* __restrict__ mk,
                                               u16* __restrict__ ctx) {
    __shared__ u16 sK[2][128 * 64];   // [kk][d], swizzled, double-buffered
    __shared__ u16 sV[2][64 * 128];   // [d][kk], swizzled, double-buffered
    __shared__ u16 sP[4][16 * 128];   // per-wave [q=lr][k], unit-swizzled
    const int tid = threadIdx.x, lane = tid & 63, wid = tid >> 6;
    const int g = lane >> 4, lr = lane & 15, swz = lr & 7;
    const int q0 = blockIdx.x * 128, h = blockIdx.y, b = blockIdx.z;
    const u16* qb = Q + ((size_t)(b * H_ + h) * S_ + q0) * DH;
    const u16* kb = K + (size_t)(b * H_ + h) * S_ * DH;
    const u16* vb = V + (size_t)(b * H_ + h) * DH * S_;
    const unsigned* mkb = mk + (size_t)b * (S_ / 32) * S_;
    const int qrow = q0 + wid * 32 + lr;
    u16* sPw = sP[wid];

    s16x8 qf[2][2];
#pragma unroll
    for (int m = 0; m < 2; m++)
#pragma unroll
        for (int dc = 0; dc < 2; dc++)
            qf[m][dc] = *(const s16x8*)(qb + (wid * 32 + m * 16 + lr) * DH + dc * 32 + g * 8);

    f32x4 o[2][4] = {};
    float mrun[2] = {-3e38f, -3e38f}, lrun[2] = {0.f, 0.f};
    s16x8 kv[4], vv[4];

    // prologue: load + stage tile 0
#pragma unroll
    for (int p = 0; p < 4; p++) {
        int L = p * 256 + tid;
        kv[p] = *(const s16x8*)(kb + (L >> 3) * DH + (L & 7) * 8);
        vv[p] = *(const s16x8*)(vb + (L >> 4) * S_ + (L & 15) * 8);
    }
#pragma unroll
    for (int p = 0; p < 4; p++) {
        int L = p * 256 + tid;
        int rk = L >> 3, ck = L & 7;
        *(s16x8*)(sK[0] + rk * 64 + (ck ^ (rk & 7)) * 8) = kv[p];
        int rv = L >> 4, cv = L & 15;
        *(s16x8*)(sV[0] + rv * 128 + (cv ^ (rv & 7)) * 8) = vv[p];
    }
    __syncthreads();

    int cur = 0;
    for (int kt = 0; kt < S_ / 128; kt++) {
        const int k0 = kt * 128;
        // T14: issue next-tile global loads before compute
        if (kt < S_ / 128 - 1) {
            const int kn = k0 + 128;
#pragma unroll
            for (int p = 0; p < 4; p++) {
                int L = p * 256 + tid;
                kv[p] = *(const s16x8*)(kb + (kn + (L >> 3)) * DH + (L & 7) * 8);
                vv[p] = *(const s16x8*)(vb + (L >> 4) * S_ + kn + (L & 15) * 8);
            }
        }
        unsigned mw[2][4];
#pragma unroll
        for (int m = 0; m < 2; m++)
#pragma unroll
            for (int nw = 0; nw < 4; nw++)
                mw[m][nw] = mkb[((k0 >> 5) + nw) * S_ + qrow + m * 16];

        const u16* sKc = sK[cur];
        const u16* sVc = sV[cur];
        f32x4 sc[2][8];
        __builtin_amdgcn_s_setprio(1);
#pragma unroll
        for (int n = 0; n < 8; n++) {
            const u16* kr = sKc + (n * 16 + lr) * 64;
            s16x8 kf0 = *(const s16x8*)(kr + ((g) ^ swz) * 8);
            s16x8 kf1 = *(const s16x8*)(kr + ((4 + g) ^ swz) * 8);
#pragma unroll
            for (int m = 0; m < 2; m++) {
                f32x4 z = {0.f, 0.f, 0.f, 0.f};
                sc[m][n] = z;
                mfma(sc[m][n], kf0, qf[m][0]);
                mfma(sc[m][n], kf1, qf[m][1]);
            }
        }
        __builtin_amdgcn_s_setprio(0);

#pragma unroll
        for (int m = 0; m < 2; m++) {
            // mask: sc[m][n][i] is score[q=qrow+m*16][k = k0 + n*16 + g*4 + i]
#pragma unroll
            for (int nw = 0; nw < 4; nw++) {
                unsigned s0 = mw[m][nw] >> (g * 4);
                unsigned s1 = mw[m][nw] >> (16 + g * 4);
#pragma unroll
                for (int i = 0; i < 4; i++) {
                    if (!((s0 >> i) & 1u)) sc[m][nw * 2][i] = -1e9f;
                    if (!((s1 >> i) & 1u)) sc[m][nw * 2 + 1][i] = -1e9f;
                }
            }
            // row max (one q-row per lane)
            float vm = -3e38f;
#pragma unroll
            for (int n = 0; n < 8; n++)
#pragma unroll
                for (int i = 0; i < 4; i++) vm = fmaxf(vm, sc[m][n][i]);
            vm = fmaxf(vm, __shfl_xor(vm, 16));
            vm = fmaxf(vm, __shfl_xor(vm, 32));
            float mnew = fmaxf(mrun[m], vm);
            float fac = exp2f(mrun[m] - mnew);
            mrun[m] = mnew;
#pragma unroll
            for (int n = 0; n < 4; n++) o[m][n] *= fac;  // lane-uniform rescale
            float rs = 0.f;
#pragma unroll
            for (int n = 0; n < 8; n++)
#pragma unroll
                for (int i = 0; i < 4; i++) {
                    float pv = exp2f(sc[m][n][i] - mnew);
                    sc[m][n][i] = pv;
                    rs += pv;
                }
            rs += __shfl_xor(rs, 16);
            rs += __shfl_xor(rs, 32);
            lrun[m] = lrun[m] * fac + rs;
            // pack P pairs (i is k-consecutive) -> wave-private LDS, unit-XOR swizzle
#pragma unroll
            for (int n = 0; n < 8; n++) {
                u32x2 wp;
                wp.x = cvtpk(sc[m][n][0], sc[m][n][1]);
                wp.y = cvtpk(sc[m][n][2], sc[m][n][3]);
                int unit = (n * 2 + (g >> 1)) ^ swz;
                *(u32x2*)(sPw + lr * 128 + unit * 8 + (g & 1) * 4) = wp;
            }
            // PV
            __builtin_amdgcn_s_setprio(1);
#pragma unroll
            for (int kc = 0; kc < 4; kc++) {
                s16x8 pb = *(const s16x8*)(sPw + lr * 128 + ((kc * 4 + g) ^ swz) * 8);
#pragma unroll
                for (int n = 0; n < 4; n++) {
                    s16x8 vf = *(const s16x8*)(sVc + (n * 16 + lr) * 128 + ((kc * 4 + g) ^ swz) * 8);
                    mfma(o[m][n], vf, pb);
                }
            }
            __builtin_amdgcn_s_setprio(0);
        }
        // T14: write staged regs into the other buffer, single barrier/tile
        if (kt < S_ / 128 - 1) {
#pragma unroll
            for (int p = 0; p < 4; p++) {
                int L = p * 256 + tid;
                int rk = L >> 3, ck = L & 7;
                *(s16x8*)(sK[cur ^ 1] + rk * 64 + (ck ^ (rk & 7)) * 8) = kv[p];
                int rv = L >> 4, cv = L & 15;
                *(s16x8*)(sV[cur ^ 1] + rv * 128 + (cv ^ (rv & 7)) * 8) = vv[p];
            }
            __syncthreads();
            cur ^= 1;
        }
    }
    // epilogue: o[m][n][i] = out[q=lr][d = n*16+g*4+i]; pack 4 consecutive d
#pragma unroll
    for (int m = 0; m < 2; m++) {
        float inv = 1.f / lrun[m];
        int q = q0 + wid * 32 + m * 16 + lr;
#pragma unroll
        for (int n = 0; n < 4; n++) {
            u16x4 pk;
#pragma unroll
            for (int i = 0; i < 4; i++) pk[i] = f2bf(o[m][n][i] * inv);
            *(u16x4*)(ctx + ((size_t)(b * S_ + q)) * E_ + h * DH + n * 16 + g * 4) = pk;
        }
    }
}

// ---- launch -------------------------------------------------------------

extern "C" void kernel_launch(void* const* d_in, const int* in_sizes, int n_in,
                              void* d_out, int out_size, void* d_ws, size_t ws_size,
                              hipStream_t stream) {
    const float* x  = (const float*)d_in[0];
    const int* mask = (const int*)d_in[1];
    const float* Wq = (const float*)d_in[2]; const float* bq = (const float*)d_in[3];
    const float* Wk = (const float*)d_in[4]; const float* bk = (const float*)d_in[5];
    const float* Wv = (const float*)d_in[6]; const float* bv = (const float*)d_in[7];
    const float* Wo = (const float*)d_in[8]; const float* bo = (const float*)d_in[9];
    float* out = (float*)d_out;

    char* ws = (char*)d_ws;
    u16* xb     = (u16*)(ws);                      // 8 MB  [M,E] bf16
    u16* Wqkvt  = (u16*)(ws + (8u  << 20));        // 6 MB  [3072,1024] fused B^T
    u16* Wot    = (u16*)(ws + (14u << 20));        // 2 MB
    u16* Qh     = (u16*)(ws + (16u << 20));        // 8 MB  [B,H,S,64] (pre-scaled)
    u16* Kh     = (u16*)(ws + (24u << 20));        // 8 MB  [B,H,S,64]
    u16* Vt     = (u16*)(ws + (32u << 20));        // 8 MB  [B,H,64,S]
    u16* ctx    = (u16*)(ws + (40u << 20));        // 8 MB  [M,E]
    unsigned* mk = (unsigned*)(ws + (48u << 20));  // 1 MB  k-packed mask

    cvt_bf16<<<(M_ * E_ / 4 + 255) / 256, 256, 0, stream>>>(x, xb, M_ * E_ / 4);
    dim3 tg(E_ / 64, E_ / 64);
    wtrans<<<tg, 256, 0, stream>>>(Wq, Wqkvt);
    wtrans<<<tg, 256, 0, stream>>>(Wk, Wqkvt + 1024 * 1024);
    wtrans<<<tg, 256, 0, stream>>>(Wv, Wqkvt + 2 * 1024 * 1024);
    wtrans<<<tg, 256, 0, stream>>>(Wo, Wot);
    mpackK<<<(B_ * 64 * S_) / 256, 256, 0, stream>>>(mask, mk);

    proj<0><<<(M_ / 128) * (3072 / 128), 256, 0, stream>>>(xb, Wqkvt, bq, bk, bv,
                                                           Qh, Kh, Vt, nullptr);

    attn<<<dim3(S_ / 128, H_, B_), 256, 0, stream>>>(Qh, Kh, Vt, mk, ctx);

    proj<3><<<(M_ / 128) * (E_ / 128), 256, 0, stream>>>(ctx, Wot, bo, nullptr, nullptr,
                                                         nullptr, nullptr, nullptr, out);
}

// Round 3
// 166.507 us; speedup vs baseline: 1.4236x; 1.1420x over previous
//
#include <hip/hip_runtime.h>

typedef float f32x4 __attribute__((ext_vector_type(4)));
typedef short s16x8 __attribute__((ext_vector_type(8)));
typedef unsigned short u16;
typedef unsigned short u16x4 __attribute__((ext_vector_type(4)));
typedef unsigned int u32x2 __attribute__((ext_vector_type(2)));

#define DI __device__ __forceinline__

constexpr int B_ = 2, S_ = 2048, E_ = 1024, H_ = 16, DH = 64, M_ = B_ * S_;
// 1/sqrt(64) * log2(e): scores land in log2 domain -> exp2f for softmax
constexpr float QSCALE = 0.125f * 1.4426950408889634f;

DI u16 f2bf(float f) {
    unsigned u = __float_as_uint(f);
    u += 0x7fffu + ((u >> 16) & 1u);
    return (u16)(u >> 16);
}

DI unsigned cvtpk(float lo, float hi) {
    unsigned r;
    asm("v_cvt_pk_bf16_f32 %0, %1, %2" : "=v"(r) : "v"(lo), "v"(hi));
    return r;
}

DI void mfma(f32x4& d, s16x8 a, s16x8 b) {
    asm("v_mfma_f32_16x16x32_bf16 %0, %1, %2, %0" : "+v"(d) : "v"(a), "v"(b));
}

typedef __attribute__((address_space(1))) const void gas_cv;
typedef __attribute__((address_space(3))) void las_v;
// async global->LDS, 16B per lane; l must be wave-uniform (HW adds lane*16)
DI void gl16(const void* g, void* l) {
    __builtin_amdgcn_global_load_lds((gas_cv*)g, (las_v*)l, 16, 0, 0);
}

// ---- preprocess kernels -------------------------------------------------

__global__ __launch_bounds__(256) void cvt_bf16(const float* __restrict__ in,
                                                u16* __restrict__ out, int n4) {
    int i = blockIdx.x * 256 + threadIdx.x;
    if (i < n4) {
        float4 v = ((const float4*)in)[i];
        u16x4 o;
        o.x = f2bf(v.x); o.y = f2bf(v.y); o.z = f2bf(v.z); o.w = f2bf(v.w);
        ((u16x4*)out)[i] = o;
    }
}

// W [K=E][N=E] f32 -> Wt [N][K] bf16
__global__ __launch_bounds__(256) void wtrans(const float* __restrict__ in,
                                              u16* __restrict__ out) {
    __shared__ float t[64][65];
    int k0 = blockIdx.x * 64, n0 = blockIdx.y * 64;
    int tx = threadIdx.x & 63, ty = threadIdx.x >> 6;
#pragma unroll
    for (int i = 0; i < 16; i++) {
        int r = i * 4 + ty;
        t[r][tx] = in[(k0 + r) * E_ + n0 + tx];
    }
    __syncthreads();
#pragma unroll
    for (int i = 0; i < 16; i++) {
        int r = i * 4 + ty;
        out[(n0 + r) * E_ + k0 + tx] = f2bf(t[tx][r]);
    }
}

// mask [B][S][S] int -> k-packed words mk[b][k>>5][q], bit = k&31
__global__ __launch_bounds__(256) void mpackK(const int* __restrict__ mask,
                                              unsigned* __restrict__ mk) {
    int t = blockIdx.x * 256 + threadIdx.x;  // (b, kw, q), q fastest
    int q = t & (S_ - 1);
    int kw = (t >> 11) & 63;
    int b = t >> 17;
    const int* mp = mask + ((size_t)(b * S_ + q)) * S_ + kw * 32;
    unsigned w = 0;
#pragma unroll
    for (int j = 0; j < 32; j++) w |= (mp[j] != 0 ? 1u : 0u) << j;
    mk[t] = w;
}

// ---- 128x128 bf16 MFMA GEMM, B^T input, global_load_lds staging ---------
// MODE 0: fused QKV (Bt rows 0..3071; epilogue routes by region)
// MODE 3: O-proj (f32 out [M,E])
template <int MODE>
__global__ __launch_bounds__(256) void proj(const u16* __restrict__ A,
                                            const u16* __restrict__ Bt,
                                            const float* __restrict__ b0,
                                            const float* __restrict__ b1,
                                            const float* __restrict__ b2,
                                            u16* __restrict__ Qh, u16* __restrict__ Kh,
                                            u16* __restrict__ Vt,
                                            float* __restrict__ of) {
    __shared__ u16 sA[128 * 32], sB[128 * 32];  // linear (gload_lds fills lane-order)
    const int tid = threadIdx.x, lane = tid & 63, wid = tid >> 6;
    const int g = lane >> 4, lr = lane & 15;
    const int wr = wid >> 1, wc = wid & 1;
    constexpr int NCT = (MODE == 0) ? 24 : 8;
    const int nblk = (M_ / 128) * NCT;
    const int cpx = nblk / 8;
    const int sw = (blockIdx.x & 7) * cpx + (blockIdx.x >> 3);  // XCD-chunked
    const int rt = sw / NCT, ct = sw % NCT;
    const int row0 = rt * 128, col0 = ct * 128;

    // per-lane source row/col for staging (4 lanes x 16B = one 64B tile row)
    const int srow = wid * 32 + (lane >> 2);
    const int scol = (lane & 3) * 8;

    f32x4 acc[4][4] = {};
    for (int kt = 0; kt < E_ / 32; kt++) {
        int k0 = kt * 32;
        __syncthreads();  // previous tile fully consumed
#pragma unroll
        for (int j = 0; j < 2; j++) {
            gl16(A  + (size_t)(row0 + srow + j * 16) * E_ + k0 + scol,
                 sA + wid * 1024 + j * 512);
            gl16(Bt + (size_t)(col0 + srow + j * 16) * E_ + k0 + scol,
                 sB + wid * 1024 + j * 512);
        }
        __syncthreads();  // drains vmcnt(0): tile visible
        s16x8 af[4], bfr[4];
#pragma unroll
        for (int m = 0; m < 4; m++)
            af[m] = *(const s16x8*)(sA + (wr * 64 + m * 16 + lr) * 32 + g * 8);
#pragma unroll
        for (int n = 0; n < 4; n++)
            bfr[n] = *(const s16x8*)(sB + (wc * 64 + n * 16 + lr) * 32 + g * 8);
        __builtin_amdgcn_s_setprio(1);
#pragma unroll
        for (int m = 0; m < 4; m++)
#pragma unroll
            for (int n = 0; n < 4; n++) mfma(acc[m][n], af[m], bfr[n]);
        __builtin_amdgcn_s_setprio(0);
    }

    if constexpr (MODE == 3) {
#pragma unroll
        for (int n = 0; n < 4; n++) {
            int c = col0 + wc * 64 + n * 16 + lr;
            float bb = b0[c];
#pragma unroll
            for (int m = 0; m < 4; m++) {
                int rb = row0 + wr * 64 + m * 16 + g * 4;
#pragma unroll
                for (int i = 0; i < 4; i++) of[(size_t)(rb + i) * E_ + c] = acc[m][n][i] + bb;
            }
        }
    } else {
        const int region = col0 >> 10;  // block-uniform: 0=Q 1=K 2=V
        const float* bias = region == 0 ? b0 : (region == 1 ? b1 : b2);
        const float scl = region == 0 ? QSCALE : 1.0f;
        u16* dst = region == 0 ? Qh : Kh;
#pragma unroll
        for (int n = 0; n < 4; n++) {
            int ccol = (col0 & 1023) + wc * 64 + n * 16 + lr;  // 0..1023
            float bb = bias[ccol];
            int h = ccol >> 6, dh = ccol & 63;
#pragma unroll
            for (int m = 0; m < 4; m++) {
                int rb = row0 + wr * 64 + m * 16 + g * 4;
                int b = rb >> 11, s = rb & (S_ - 1);
                if (region == 2) {
                    u16x4 pk;
                    pk.x = f2bf(acc[m][n][0] + bb);
                    pk.y = f2bf(acc[m][n][1] + bb);
                    pk.z = f2bf(acc[m][n][2] + bb);
                    pk.w = f2bf(acc[m][n][3] + bb);
                    *(u16x4*)(Vt + ((size_t)((b * H_ + h) * DH + dh)) * S_ + s) = pk;
                } else {
#pragma unroll
                    for (int i = 0; i < 4; i++) {
                        int r = rb + i, bb2 = r >> 11, s2 = r & (S_ - 1);
                        dst[((size_t)((bb2 * H_ + h) * S_) + s2) * DH + dh] =
                            f2bf((acc[m][n][i] + bb) * scl);
                    }
                }
            }
        }
    }
}

// ---- flash attention, swapped-operand, QBLK=64 KVBLK=64 ------------------
// grid 1024 flat (XCD-swizzled), 256 threads = 4 waves x 16 q-rows.
// QK^T: mfma(A=K, B=Q) -> lane holds scores for q = lr (k in regs).
// PV:   mfma(A=V^T, B=P) -> o[q=lr][d in regs]; rescale lane-uniform.
__global__ __launch_bounds__(256, 4) void attn(const u16* __restrict__ Q,
                                               const u16* __restrict__ K,
                                               const u16* __restrict__ V,
                                               const unsigned* __restrict__ mk,
                                               u16* __restrict__ ctx) {
    __shared__ u16 sK[2][64 * 64];   // [kk][d], swizzled, double-buffered
    __shared__ u16 sV[2][64 * 64];   // [d][kk], swizzled, double-buffered
    __shared__ u16 sP[4][16 * 64];   // per-wave [q=lr][k], unit-swizzled
    const int tid = threadIdx.x, lane = tid & 63, wid = tid >> 6;
    const int g = lane >> 4, lr = lane & 15, swz = lr & 7;
    // XCD-chunked swizzle: 1024 blocks, q fastest -> same-XCD blocks share (b,h)
    const int swg = (blockIdx.x & 7) * 128 + (blockIdx.x >> 3);
    const int q0 = (swg & 31) * 64, h = (swg >> 5) & 15, b = swg >> 9;
    const u16* qb = Q + ((size_t)(b * H_ + h) * S_ + q0) * DH;
    const u16* kb = K + (size_t)(b * H_ + h) * S_ * DH;
    const u16* vb = V + (size_t)(b * H_ + h) * DH * S_;
    const unsigned* mkb = mk + (size_t)b * (S_ / 32) * S_;
    const int qrow = q0 + wid * 16 + lr;
    u16* sPw = sP[wid];

    s16x8 qf[2];
#pragma unroll
    for (int dc = 0; dc < 2; dc++)
        qf[dc] = *(const s16x8*)(qb + (wid * 16 + lr) * DH + dc * 32 + g * 8);

    f32x4 o[4] = {};
    float mrun = -3e38f, lrun = 0.f;
    s16x8 kv[2], vv[2];

    // prologue: load + stage tile 0
#pragma unroll
    for (int p = 0; p < 2; p++) {
        int L = p * 256 + tid;
        kv[p] = *(const s16x8*)(kb + (L >> 3) * DH + (L & 7) * 8);
        vv[p] = *(const s16x8*)(vb + (L >> 3) * S_ + (L & 7) * 8);
    }
#pragma unroll
    for (int p = 0; p < 2; p++) {
        int L = p * 256 + tid;
        int rr = L >> 3, cc = L & 7;
        *(s16x8*)(sK[0] + rr * 64 + (cc ^ (rr & 7)) * 8) = kv[p];
        *(s16x8*)(sV[0] + rr * 64 + (cc ^ (rr & 7)) * 8) = vv[p];
    }
    __syncthreads();

    int cur = 0;
    for (int kt = 0; kt < S_ / 64; kt++) {
        const int k0 = kt * 64;
        // T14: issue next-tile global loads before compute
        if (kt < S_ / 64 - 1) {
            const int kn = k0 + 64;
#pragma unroll
            for (int p = 0; p < 2; p++) {
                int L = p * 256 + tid;
                kv[p] = *(const s16x8*)(kb + (kn + (L >> 3)) * DH + (L & 7) * 8);
                vv[p] = *(const s16x8*)(vb + (L >> 3) * S_ + kn + (L & 7) * 8);
            }
        }
        unsigned mw[2];
#pragma unroll
        for (int nw = 0; nw < 2; nw++)
            mw[nw] = mkb[((k0 >> 5) + nw) * S_ + qrow];

        const u16* sKc = sK[cur];
        const u16* sVc = sV[cur];
        f32x4 sc[4];
        __builtin_amdgcn_s_setprio(1);
#pragma unroll
        for (int n = 0; n < 4; n++) {
            const u16* kr = sKc + (n * 16 + lr) * 64;
            s16x8 kf0 = *(const s16x8*)(kr + (g ^ swz) * 8);
            s16x8 kf1 = *(const s16x8*)(kr + ((4 + g) ^ swz) * 8);
            f32x4 z = {0.f, 0.f, 0.f, 0.f};
            sc[n] = z;
            mfma(sc[n], kf0, qf[0]);
            mfma(sc[n], kf1, qf[1]);
        }
        __builtin_amdgcn_s_setprio(0);

        // mask: sc[n][i] is score[q=qrow][k = k0 + n*16 + g*4 + i]
#pragma unroll
        for (int n = 0; n < 4; n++) {
            unsigned sb = mw[n >> 1] >> ((n & 1) * 16 + g * 4);
#pragma unroll
            for (int i = 0; i < 4; i++)
                if (!((sb >> i) & 1u)) sc[n][i] = -1e9f;
        }
        // online softmax with defer-max (T13, THR=8 in log2 domain)
        float vm = -3e38f;
#pragma unroll
        for (int n = 0; n < 4; n++)
#pragma unroll
            for (int i = 0; i < 4; i++) vm = fmaxf(vm, sc[n][i]);
        vm = fmaxf(vm, __shfl_xor(vm, 16));
        vm = fmaxf(vm, __shfl_xor(vm, 32));
        if (!__all(vm <= mrun + 8.f)) {
            float mnew = fmaxf(mrun, vm);
            float fac = exp2f(mrun - mnew);
            mrun = mnew;
#pragma unroll
            for (int n = 0; n < 4; n++) o[n] *= fac;
            lrun *= fac;
        }
        float rs = 0.f;
#pragma unroll
        for (int n = 0; n < 4; n++)
#pragma unroll
            for (int i = 0; i < 4; i++) {
                float pv = exp2f(sc[n][i] - mrun);
                sc[n][i] = pv;
                rs += pv;
            }
        rs += __shfl_xor(rs, 16);
        rs += __shfl_xor(rs, 32);
        lrun += rs;
        // pack P pairs -> wave-private LDS [16 q][64 k], 16B-unit XOR swizzle
#pragma unroll
        for (int n = 0; n < 4; n++) {
            u32x2 wp;
            wp.x = cvtpk(sc[n][0], sc[n][1]);
            wp.y = cvtpk(sc[n][2], sc[n][3]);
            int unit = (n * 2 + (g >> 1)) ^ swz;
            *(u32x2*)(sPw + lr * 64 + unit * 8 + (g & 1) * 4) = wp;
        }
        // PV
        __builtin_amdgcn_s_setprio(1);
#pragma unroll
        for (int kc = 0; kc < 2; kc++) {
            s16x8 pb = *(const s16x8*)(sPw + lr * 64 + ((kc * 4 + g) ^ swz) * 8);
#pragma unroll
            for (int n = 0; n < 4; n++) {
                int rv = n * 16 + lr;
                s16x8 vf = *(const s16x8*)(sVc + rv * 64 + ((kc * 4 + g) ^ (rv & 7)) * 8);
                mfma(o[n], vf, pb);
            }
        }
        __builtin_amdgcn_s_setprio(0);
        // T14: write staged regs into the other buffer, single barrier/tile
        if (kt < S_ / 64 - 1) {
#pragma unroll
            for (int p = 0; p < 2; p++) {
                int L = p * 256 + tid;
                int rr = L >> 3, cc = L & 7;
                *(s16x8*)(sK[cur ^ 1] + rr * 64 + (cc ^ (rr & 7)) * 8) = kv[p];
                *(s16x8*)(sV[cur ^ 1] + rr * 64 + (cc ^ (rr & 7)) * 8) = vv[p];
            }
            __syncthreads();
            cur ^= 1;
        }
    }
    // epilogue: transpose O through sPw -> coalesced 16B/lane ctx stores
    {
        float inv = 1.f / lrun;
#pragma unroll
        for (int n = 0; n < 4; n++) {
            u16x4 pk;
#pragma unroll
            for (int i = 0; i < 4; i++) pk[i] = f2bf(o[n][i] * inv);
            *(u16x4*)(sPw + lr * 64 + n * 16 + g * 4) = pk;
        }
#pragma unroll
        for (int half = 0; half < 2; half++) {
            int rr = half * 8 + (lane >> 3);
            s16x8 v = *(const s16x8*)(sPw + rr * 64 + (lane & 7) * 8);
            int q = q0 + wid * 16 + rr;
            *(s16x8*)(ctx + ((size_t)(b * S_ + q)) * E_ + h * DH + (lane & 7) * 8) = v;
        }
    }
}

// ---- launch -------------------------------------------------------------

extern "C" void kernel_launch(void* const* d_in, const int* in_sizes, int n_in,
                              void* d_out, int out_size, void* d_ws, size_t ws_size,
                              hipStream_t stream) {
    const float* x  = (const float*)d_in[0];
    const int* mask = (const int*)d_in[1];
    const float* Wq = (const float*)d_in[2]; const float* bq = (const float*)d_in[3];
    const float* Wk = (const float*)d_in[4]; const float* bk = (const float*)d_in[5];
    const float* Wv = (const float*)d_in[6]; const float* bv = (const float*)d_in[7];
    const float* Wo = (const float*)d_in[8]; const float* bo = (const float*)d_in[9];
    float* out = (float*)d_out;

    char* ws = (char*)d_ws;
    u16* xb     = (u16*)(ws);                      // 8 MB  [M,E] bf16
    u16* Wqkvt  = (u16*)(ws + (8u  << 20));        // 6 MB  [3072,1024] fused B^T
    u16* Wot    = (u16*)(ws + (14u << 20));        // 2 MB
    u16* Qh     = (u16*)(ws + (16u << 20));        // 8 MB  [B,H,S,64] (pre-scaled)
    u16* Kh     = (u16*)(ws + (24u << 20));        // 8 MB  [B,H,S,64]
    u16* Vt     = (u16*)(ws + (32u << 20));        // 8 MB  [B,H,64,S]
    u16* ctx    = (u16*)(ws + (40u << 20));        // 8 MB  [M,E]
    unsigned* mk = (unsigned*)(ws + (48u << 20));  // 1 MB  k-packed mask

    cvt_bf16<<<(M_ * E_ / 4 + 255) / 256, 256, 0, stream>>>(x, xb, M_ * E_ / 4);
    dim3 tg(E_ / 64, E_ / 64);
    wtrans<<<tg, 256, 0, stream>>>(Wq, Wqkvt);
    wtrans<<<tg, 256, 0, stream>>>(Wk, Wqkvt + 1024 * 1024);
    wtrans<<<tg, 256, 0, stream>>>(Wv, Wqkvt + 2 * 1024 * 1024);
    wtrans<<<tg, 256, 0, stream>>>(Wo, Wot);
    mpackK<<<(B_ * 64 * S_) / 256, 256, 0, stream>>>(mask, mk);

    proj<0><<<(M_ / 128) * (3072 / 128), 256, 0, stream>>>(xb, Wqkvt, bq, bk, bv,
                                                           Qh, Kh, Vt, nullptr);

    attn<<<(S_ / 64) * H_ * B_, 256, 0, stream>>>(Qh, Kh, Vt, mk, ctx);

    proj<3><<<(M_ / 128) * (E_ / 128), 256, 0, stream>>>(ctx, Wot, bo, nullptr, nullptr,
                                                         nullptr, nullptr, nullptr, out);
}